// Round 8
// baseline (1939.191 us; speedup 1.0000x reference)
//
#include <hip/hip_runtime.h>
#include <math.h>

#define SS 512
#define BB 64
#define TT 256
#define AG __HIP_MEMORY_SCOPE_AGENT

typedef float f4 __attribute__((ext_vector_type(4)));
typedef short s8v __attribute__((ext_vector_type(8)));
typedef unsigned long long u64;
typedef unsigned short u16;

__device__ __forceinline__ float wredsum(float v) {
#pragma unroll
  for (int o = 32; o; o >>= 1) v += __shfl_xor(v, o);
  return v;
}
// LLC-coherent (sc0 sc1) accesses, no cache-maintenance emitted.
__device__ __forceinline__ u64 ld8(const u64* p) {
  return __hip_atomic_load((u64*)p, __ATOMIC_RELAXED, AG);
}
__device__ __forceinline__ void st8(u64* p, u64 v) {
  __hip_atomic_store(p, v, __ATOMIC_RELAXED, AG);
}
__device__ __forceinline__ void st4(float* p, float v) {
  __hip_atomic_store(p, v, __ATOMIC_RELAXED, AG);
}
__device__ __forceinline__ float ld4(const float* p) {
  return __hip_atomic_load((float*)p, __ATOMIC_RELAXED, AG);
}
__device__ __forceinline__ u16 f2bf(float f) {  // RNE f32->bf16 (no NaN here)
  unsigned u = __float_as_uint(f);
  return (u16)((u + 0x7fffu + ((u >> 16) & 1u)) >> 16);
}
__device__ __forceinline__ s8v mk8(u64 lo, u64 hi) {
  union { u64 u[2]; s8v v; } t;
  t.u[0] = lo; t.u[1] = hi;
  return t.v;
}

// ---------------- setup kernels (regular launches; boundary = coherence) ----
__global__ void k_init(float* out, float* colsum, unsigned* bar) {
  const int t = threadIdx.x;  // 512
  if (t == 0) out[0] = 0.f;
  colsum[t] = 0.f;
  bar[t] = 0u;
}

__global__ void k_colpart(const float* __restrict__ iw, float* __restrict__ psum) {
  const int blk = blockIdx.x;   // 250
  const int tid = threadIdx.x;  // 256
  const int cg = tid & 127;
  const int rh = tid >> 7;
  const int r0 = blk * 128 + rh * 64;
  const f4* iw4 = (const f4*)iw;  // [32000][128]
  f4 s = {};
#pragma unroll 4
  for (int r = 0; r < 64; ++r) {
    f4 x = iw4[(size_t)(r0 + r) * 128 + cg];
    s.x += __expf(x.x); s.y += __expf(x.y);
    s.z += __expf(x.z); s.w += __expf(x.w);
  }
  ((f4*)psum)[(size_t)(blk * 2 + rh) * 128 + cg] = s;
}

__global__ void k_colreduce(const float* __restrict__ psum, float* __restrict__ colsum) {
  const int c = threadIdx.x;  // 512
  const int p0 = blockIdx.x * 20;  // 25 blocks
  float s = 0.f;
#pragma unroll 5
  for (int p = 0; p < 20; ++p) s += psum[(size_t)(p0 + p) * SS + c];
  atomicAdd(&colsum[c], s);
}

__global__ void k_lse(const float* __restrict__ colsum, float* __restrict__ colLSE) {
  colLSE[threadIdx.x] = __logf(colsum[threadIdx.x]);
}

// P softmax rows -> bf16 (blocks 0..127, 4 rows each); block 128: sb + ring
// slab-1 prefill (both chains) so step-0 GEMM produces q0 = P . sb.
__global__ void k_prep(const float* __restrict__ trans, const float* __restrict__ begin,
                       u16* __restrict__ Pbf, u64* __restrict__ ring) {
  const int blk = blockIdx.x;
  const int tid = threadIdx.x;
  const int lane = tid & 63;
  const int h = tid >> 6;
  __shared__ float sb_l[512];
  if (blk < 128) {
    const int i = blk * 4 + h;
    const float* rp = trans + (size_t)i * SS;
    float xs[8];
    float m = -1e30f;
#pragma unroll
    for (int cc = 0; cc < 8; ++cc) { xs[cc] = rp[cc * 64 + lane]; m = fmaxf(m, xs[cc]); }
#pragma unroll
    for (int o = 32; o; o >>= 1) m = fmaxf(m, __shfl_xor(m, o));
    float s = 0.f;
#pragma unroll
    for (int cc = 0; cc < 8; ++cc) s += __expf(xs[cc] - m);
#pragma unroll
    for (int o = 32; o; o >>= 1) s += __shfl_xor(s, o);
    const float lse = m + __logf(s);
#pragma unroll
    for (int cc = 0; cc < 8; ++cc)
      Pbf[(size_t)i * SS + cc * 64 + lane] = f2bf(__expf(xs[cc] - lse));
  } else {
    if (h == 0) {
      float xs[8];
      float m = -1e30f;
#pragma unroll
      for (int cc = 0; cc < 8; ++cc) { xs[cc] = begin[cc * 64 + lane]; m = fmaxf(m, xs[cc]); }
#pragma unroll
      for (int o = 32; o; o >>= 1) m = fmaxf(m, __shfl_xor(m, o));
      float s = 0.f;
#pragma unroll
      for (int cc = 0; cc < 8; ++cc) s += __expf(xs[cc] - m);
#pragma unroll
      for (int o = 32; o; o >>= 1) s += __shfl_xor(s, o);
      const float inv = 1.f / s;
#pragma unroll
      for (int cc = 0; cc < 8; ++cc) sb_l[cc * 64 + lane] = __expf(xs[cc] - m) * inv;
    }
    __syncthreads();
    for (int u = tid; u < 8192; u += 256) {  // slab = 8192 u64 (64x512 bf16)
      const int jg = u & 127;
      const u64 v = (u64)f2bf(sb_l[jg * 4 + 0]) | ((u64)f2bf(sb_l[jg * 4 + 1]) << 16) |
                    ((u64)f2bf(sb_l[jg * 4 + 2]) << 32) | ((u64)f2bf(sb_l[jg * 4 + 3]) << 48);
      ring[1 * 8192 + u] = v;  // chain0 slab1
      ring[3 * 8192 + u] = v;  // chain1 slab1
    }
  }
}

// ---------------- persistent main: 16 blocks x 512 thr ----------------------
// chain = blk&1 (8 blocks each), grp = blk>>1, block owns 64 cols c0=grp*64.
// Wave w: m-tile mt=w&3 (16 batch rows), n-half nh=w>>2 (2x16 cols).
// B fragments (P) live in VGPRs for the whole kernel. A (wn) from LLC ring.
__global__ __launch_bounds__(512, 2) void k_main(
    const int* __restrict__ sent, const float* __restrict__ masks,
    const float* __restrict__ iw, const u16* __restrict__ Pbf,
    const float* __restrict__ colLSE, u64* __restrict__ ring,
    float* __restrict__ part, float* __restrict__ out,
    unsigned* __restrict__ bar) {
  const int blk = blockIdx.x;
  const int tid = threadIdx.x;
  const int lane = tid & 63;
  const int w = __builtin_amdgcn_readfirstlane(tid >> 6);  // 0..7
  const int chain = blk & 1;
  const int grp = blk >> 1;  // 0..7
  const int c0 = grp * 64;
  const int mt = w & 3, nh = w >> 2;
  const int m0 = mt * 16;
  const int lx = lane & 15, quad = lane >> 4;

  __shared__ float q_lds[64 * 65];   // q[b][il], pad 65 (bank-friendly)
  __shared__ float dpred[8][64];
  __shared__ float cl_l[64];

  unsigned* cells = bar + chain * 256;  // 8 cells, 128B apart, monotonic
  u64* ringc = ring + (size_t)chain * 2 * 8192;
  const int smax = 129 - chain;

  if (tid < 64) cl_l[tid] = colLSE[c0 + tid];

  // preload B fragments: B[k][n] = P[c0+n][k]; lane n=lx, k=kt*32+quad*8
  s8v Bf[2][16];
#pragma unroll
  for (int nt = 0; nt < 2; ++nt) {
    const int i = c0 + (nh * 2 + nt) * 16 + lx;
    const u16* pr = Pbf + (size_t)i * SS + quad * 8;
#pragma unroll
    for (int kt = 0; kt < 16; ++kt) Bf[nt][kt] = *(const s8v*)(pr + kt * 32);
  }
  __syncthreads();

  for (int s = 0; s < smax; ++s) {
    const u64* wsrc = ringc + (size_t)((s + 1) & 1) * 8192;
    u64* wdst = ringc + (size_t)(s & 1) * 8192;
    const int tw = 2 * s + chain;
    const int td = tw - 1;
    const bool doW = (tw <= 254);
    const bool doD = (td >= 0);

    // prefetch scattered iw gathers for the 8 tail cols (c0 + w*8 ..)
    f4 ivW0 = {}, ivW1 = {}, ivD0 = {}, ivD1 = {};
    if (doW) {
      const int row = sent[lane * TT + tw];
      const f4* p = (const f4*)(iw + (size_t)row * SS + c0 + w * 8);
      ivW0 = p[0]; ivW1 = p[1];
    }
    if (doD) {
      const int row = sent[lane * TT + td];
      const f4* p = (const f4*)(iw + (size_t)row * SS + c0 + w * 8);
      ivD0 = p[0]; ivD1 = p[1];
    }

    // A fragments from LLC ring: A[m=lx][k=quad*8+j], row-major wn[b][512] bf16
    const u64* abase = wsrc + (size_t)(m0 + lx) * 128 + quad * 2;
    u64 alo[16], ahi[16];
#pragma unroll
    for (int kt = 0; kt < 16; ++kt) {
      alo[kt] = ld8(abase + kt * 8);
      ahi[kt] = ld8(abase + kt * 8 + 1);
    }
    f4 acc0 = {}, acc1 = {};
#pragma unroll
    for (int kt = 0; kt < 16; ++kt) {
      const s8v A = mk8(alo[kt], ahi[kt]);
      acc0 = __builtin_amdgcn_mfma_f32_16x16x32_bf16(A, Bf[0][kt], acc0, 0, 0, 0);
      acc1 = __builtin_amdgcn_mfma_f32_16x16x32_bf16(A, Bf[1][kt], acc1, 0, 0, 0);
    }
    // D (col=lx, row=quad*4+reg) -> LDS q[b][il]
#pragma unroll
    for (int reg = 0; reg < 4; ++reg) {
      const int b = m0 + quad * 4 + reg;
      q_lds[b * 65 + (nh * 2 + 0) * 16 + lx] = acc0[reg];
      q_lds[b * 65 + (nh * 2 + 1) * 16 + lx] = acc1[reg];
    }
    __syncthreads();

    // tail: wave w handles cols il = w*8 .. w*8+8, lane = batch b
    float dpacc = 0.f;
    u16 wnb[8];
    const float ivW[8] = {ivW0.x, ivW0.y, ivW0.z, ivW0.w, ivW1.x, ivW1.y, ivW1.z, ivW1.w};
    const float ivD[8] = {ivD0.x, ivD0.y, ivD0.z, ivD0.w, ivD1.x, ivD1.y, ivD1.z, ivD1.w};
#pragma unroll
    for (int cc = 0; cc < 8; ++cc) {
      const int il = w * 8 + cc;
      const float q = q_lds[lane * 65 + il];
      const float cl = cl_l[il];
      if (doW) {
        const float wv = q * __expf(ivW[cc] - cl);
        const float cs = wredsum(wv);  // colsum over batch (lanes)
        wnb[cc] = f2bf(wv / cs);
      }
      if (doD) dpacc += q * __expf(ivD[cc] - cl);
    }
    if (doW) {
      const u64 lo = (u64)wnb[0] | ((u64)wnb[1] << 16) | ((u64)wnb[2] << 32) | ((u64)wnb[3] << 48);
      const u64 hi = (u64)wnb[4] | ((u64)wnb[5] << 16) | ((u64)wnb[6] << 32) | ((u64)wnb[7] << 48);
      u64* wp = wdst + (size_t)lane * 128 + (c0 + w * 8) / 4;
      st8(wp, lo);
      st8(wp + 1, hi);
    }
    if (doD) dpred[w][lane] = dpacc;
    __syncthreads();
    if (doD && w == 0) {
      float tot = 0.f;
#pragma unroll
      for (int g = 0; g < 8; ++g) tot += dpred[g][lane];
      const int idx = chain ? s : (s - 1);
      st4(part + (((size_t)chain * 128 + idx) * 8 + grp) * 64 + lane, tot);
    }

    // 8-block chain barrier: arrive (own cell) + vector poll (lanes 0-7, one
    // load instruction across 8 cachelines). Monotonic counters, no reset.
    __syncthreads();  // drains vmcnt -> wn/part stores are LLC-visible
    if (tid < 64) {
      if (tid == 0)
        __hip_atomic_fetch_add(&cells[grp * 32], 1u, __ATOMIC_RELAXED, AG);
      const unsigned tgt = (unsigned)(s + 1);
      for (;;) {
        unsigned v = tgt;
        if (lane < 8) v = __hip_atomic_load(&cells[lane * 32], __ATOMIC_RELAXED, AG);
        if (__ballot(v >= tgt) == ~0ull) break;
        __builtin_amdgcn_s_sleep(1);
      }
    }
    __syncthreads();
  }

  // final: own chain's 128 ppl terms; idx = grp*16 + w*2 + rr
#pragma unroll
  for (int rr = 0; rr < 2; ++rr) {
    const int idx = grp * 16 + w * 2 + rr;
    float tot = 0.f;
#pragma unroll
    for (int g = 0; g < 8; ++g)
      tot += ld4(part + (((size_t)chain * 128 + idx) * 8 + g) * 64 + lane);
    const int td = 2 * idx + (chain ? 0 : 1);
    float v = __logf(tot) * masks[lane * TT + td];
    v = wredsum(v);
    if (lane == 0) atomicAdd(out, v);
  }
}

extern "C" void kernel_launch(void* const* d_in, const int* in_sizes, int n_in,
                              void* d_out, int out_size, void* d_ws, size_t ws_size,
                              hipStream_t stream) {
  const int* sent = (const int*)d_in[0];      // [64][256] int32
  const float* masks = (const float*)d_in[1]; // [64][256]
  const float* iw = (const float*)d_in[2];    // [32000][512]
  const float* trans = (const float*)d_in[3]; // [512][512]
  const float* begin = (const float*)d_in[4]; // [512]
  float* out = (float*)d_out;
  float* ws = (float*)d_ws;

  // workspace carve (float units; u64 arrays land on 8B-aligned offsets)
  float* psum = ws;                   // 500*512 = 256000
  float* colsum = psum + 256000;      // 512
  float* colLSE = colsum + 512;       // 512
  u16* Pbf = (u16*)(colLSE + 512);    // 512*512 u16 = 131072 floats
  u64* ring = (u64*)((float*)Pbf + 131072);  // 4 slabs * 8192 u64 = 65536 floats
  float* part = (float*)ring + 65536; // 2*128*8*64 = 131072
  unsigned* bar = (unsigned*)(part + 131072);  // 512 u32

  k_init<<<1, 512, 0, stream>>>(out, colsum, bar);
  k_colpart<<<250, 256, 0, stream>>>(iw, psum);
  k_colreduce<<<25, 512, 0, stream>>>(psum, colsum);
  k_lse<<<1, 512, 0, stream>>>(colsum, colLSE);
  k_prep<<<129, 256, 0, stream>>>(trans, begin, Pbf, ring);

  void* args[] = {(void*)&sent, (void*)&masks, (void*)&iw, (void*)&Pbf,
                  (void*)&colLSE, (void*)&ring, (void*)&part, (void*)&out,
                  (void*)&bar};
  hipLaunchCooperativeKernel((void*)k_main, dim3(16), dim3(512), args, 0,
                             stream);
}